// Round 2
// baseline (279.362 us; speedup 1.0000x reference)
//
#include <hip/hip_runtime.h>

#define L 8
#define B 128
#define NL 32
#define NP 256
#define EPL_G 1024
#define ELL_G 256
#define FIN 128
#define H 256
#define OUT 2

// One block per (layer, graph). Computes per-graph degree histograms in LDS
// (edges are block-diagonal per graph), then the weighted feature aggregate
//   g[l,b,f] = (1/NL) * sum_nodes rsqrt(deg_dst) * sum_edges rsqrt(deg_src)*x[src,f]
// REL=0: protein->ligand (E=1024, NS=256). REL=1: ligand->ligand (E=256, NS=32).
template <int REL>
__global__ __launch_bounds__(512) void gather_kernel(
    const float* __restrict__ feat,            // [L, B*NS, FIN] f32
    const int* __restrict__ srcA,              // [L, B*E]
    const int* __restrict__ dstA,              // [L, B*E]
    float* __restrict__ gout)                  // [L, B, FIN]
{
    constexpr int E  = (REL == 0) ? EPL_G : ELL_G;
    constexpr int NS = (REL == 0) ? NP : NL;

    const int l   = blockIdx.x >> 7;
    const int b   = blockIdx.x & 127;
    const int tid = threadIdx.x;

    __shared__ int   s_src[E];
    __shared__ int   s_dst[E];
    __shared__ float s_w[E];
    __shared__ int   s_cnt_src[NS];
    __shared__ int   s_cnt_dst[NL];
    __shared__ float s_red[8 * FIN];

    const int* srcp = srcA + (size_t)l * (B * E) + (size_t)b * E;
    const int* dstp = dstA + (size_t)l * (B * E) + (size_t)b * E;
    const float* fbase = feat + (size_t)l * (B * NS) * FIN;

    for (int i = tid; i < NS; i += 512) s_cnt_src[i] = 0;
    for (int i = tid; i < NL; i += 512) s_cnt_dst[i] = 0;
    __syncthreads();

    // Load edges (graph-local indices) and count degrees in LDS.
    // Edges are block-diagonal per graph, so per-graph counts == global counts.
    for (int e = tid; e < E; e += 512) {
        int s = srcp[e] - b * NS;
        int d = dstp[e] - b * NL;
        s_src[e] = s;
        s_dst[e] = d;
        atomicAdd(&s_cnt_src[s], 1);
        atomicAdd(&s_cnt_dst[d], 1);
    }
    __syncthreads();

    // Per-edge weight. Referenced nodes always have count >= 1, so the
    // reference's clip(deg, 1) is a no-op for the weights we evaluate.
    for (int e = tid; e < E; e += 512) {
        s_w[e] = rsqrtf((float)s_cnt_src[s_src[e]]) *
                 rsqrtf((float)s_cnt_dst[s_dst[e]]);
    }
    __syncthreads();

    // 8 waves = 8 edge slots; 64 lanes x float2 = one 512 B feature row.
    const int lane = tid & 63;
    const int slot = tid >> 6;
    float acc0 = 0.f, acc1 = 0.f;
#pragma unroll 4
    for (int e = slot; e < E; e += 8) {
        int   s = s_src[e];        // wave-uniform (slot == wave)
        float w = s_w[e];
        float2 v = *(const float2*)(
            fbase + (size_t)(b * NS + s) * FIN + lane * 2);
        acc0 += w * v.x;
        acc1 += w * v.y;
    }
    s_red[slot * FIN + lane * 2]     = acc0;
    s_red[slot * FIN + lane * 2 + 1] = acc1;
    __syncthreads();

    if (tid < FIN) {
        float t = 0.f;
#pragma unroll
        for (int k = 0; k < 8; k++) t += s_red[k * FIN + tid];
        gout[((size_t)l * B + b) * FIN + tid] = t * (1.0f / NL);
    }
}

// Wc[l,f,o] = sum_h W[l,f,h] * W_fc[l*H+h, o]   (folds the graph-conv weight
// into the final FC; valid because graph-mean commutes with the linear map)
__global__ __launch_bounds__(256) void wcomb_kernel(
    const float* __restrict__ W_pl,
    const float* __restrict__ W_ll,
    const float* __restrict__ W_fc,
    float* __restrict__ Wc_pl, float* __restrict__ Wc_ll)
{
    const int l = blockIdx.x;
    const float* W = blockIdx.y ? W_ll : W_pl;
    float* outc    = blockIdx.y ? Wc_ll : Wc_pl;
    const int t = threadIdx.x;
    const int f = t >> 1, o = t & 1;
    const float* wrow = W + ((size_t)l * FIN + f) * H;
    const float* fc   = W_fc + (size_t)l * H * OUT + o;
    float acc = 0.f;
#pragma unroll 4
    for (int h = 0; h < H; h++)
        acc += wrow[h] * fc[h * OUT];
    outc[((size_t)l * FIN + f) * OUT + o] = acc;
}

// bias_out[o] = b_fc[o] + sum_{l,h} (b_pl[l,h] + b_ll[l,h]) * W_fc[l*H+h, o]
__global__ __launch_bounds__(256) void bias_kernel(
    const float* __restrict__ b_pl,
    const float* __restrict__ b_ll,
    const float* __restrict__ W_fc,
    const float* __restrict__ b_fc,
    float* __restrict__ bias_out)
{
    const int t = threadIdx.x;
    float a0 = 0.f, a1 = 0.f;
    for (int i = t; i < L * H; i += 256) {
        float bs = b_pl[i] + b_ll[i];
        a0 += bs * W_fc[i * OUT];
        a1 += bs * W_fc[i * OUT + 1];
    }
    __shared__ float r0[256], r1[256];
    r0[t] = a0; r1[t] = a1;
    __syncthreads();
    for (int s = 128; s > 0; s >>= 1) {
        if (t < s) { r0[t] += r0[t + s]; r1[t] += r1[t + s]; }
        __syncthreads();
    }
    if (t == 0) {
        bias_out[0] = r0[0] + b_fc[0];
        bias_out[1] = r1[0] + b_fc[1];
    }
}

// out[b,o] = sigmoid(bias_out[o] + sum_{l,f} g_pl*Wc_pl + g_ll*Wc_ll)
__global__ __launch_bounds__(256) void final_kernel(
    const float* __restrict__ g_pl, const float* __restrict__ g_ll,
    const float* __restrict__ Wc_pl, const float* __restrict__ Wc_ll,
    const float* __restrict__ bias_out, float* __restrict__ out)
{
    const int b = blockIdx.x;
    const int t = threadIdx.x;
    const int o = t >> 7, f = t & 127;
    float acc = 0.f;
#pragma unroll
    for (int l = 0; l < L; l++) {
        float gp = g_pl[((size_t)l * B + b) * FIN + f];
        float gl = g_ll[((size_t)l * B + b) * FIN + f];
        acc += gp * Wc_pl[((size_t)l * FIN + f) * OUT + o]
             + gl * Wc_ll[((size_t)l * FIN + f) * OUT + o];
    }
    __shared__ float red[256];
    red[t] = acc;
    __syncthreads();
    for (int s = 64; s > 0; s >>= 1) {
        if (f < s) red[t] += red[t + s];
        __syncthreads();
    }
    if (f == 0) {
        float x = red[o << 7] + bias_out[o];
        out[b * OUT + o] = 1.0f / (1.0f + expf(-x));
    }
}

extern "C" void kernel_launch(void* const* d_in, const int* in_sizes, int n_in,
                              void* d_out, int out_size, void* d_ws, size_t ws_size,
                              hipStream_t stream) {
    const float* feat_lig  = (const float*)d_in[0];
    const float* feat_prot = (const float*)d_in[1];
    const int* src_pl = (const int*)d_in[2];
    const int* dst_pl = (const int*)d_in[3];
    const int* src_ll = (const int*)d_in[4];
    const int* dst_ll = (const int*)d_in[5];
    const float* W_pl = (const float*)d_in[6];
    const float* b_pl = (const float*)d_in[7];
    const float* W_ll = (const float*)d_in[8];
    const float* b_ll = (const float*)d_in[9];
    const float* W_fc = (const float*)d_in[10];
    const float* b_fc = (const float*)d_in[11];
    float* out = (float*)d_out;

    float* ws       = (float*)d_ws;
    float* g_pl     = ws;                         // L*B*FIN = 131072
    float* g_ll     = g_pl + (size_t)L * B * FIN; // 131072
    float* Wc_pl    = g_ll + (size_t)L * B * FIN; // L*FIN*OUT = 2048
    float* Wc_ll    = Wc_pl + (size_t)L * FIN * OUT;
    float* bias_out = Wc_ll + (size_t)L * FIN * OUT; // 2

    gather_kernel<0><<<dim3(L * B), 512, 0, stream>>>(feat_prot, src_pl, dst_pl, g_pl);
    gather_kernel<1><<<dim3(L * B), 512, 0, stream>>>(feat_lig, src_ll, dst_ll, g_ll);
    wcomb_kernel<<<dim3(L, 2), 256, 0, stream>>>(W_pl, W_ll, W_fc, Wc_pl, Wc_ll);
    bias_kernel<<<1, 256, 0, stream>>>(b_pl, b_ll, W_fc, b_fc, bias_out);
    final_kernel<<<B, 256, 0, stream>>>(g_pl, g_ll, Wc_pl, Wc_ll, bias_out, out);
}

// Round 3
// 240.430 us; speedup vs baseline: 1.1619x; 1.1619x over previous
//
#include <hip/hip_runtime.h>

#define L 8
#define B 128
#define NL 32
#define NP 256
#define EPL_G 1024
#define ELL_G 256
#define FIN 128
#define H 256
#define OUT 2

// Blocks 0..1023:     protein->ligand aggregate, one (l,b) graph each.
// Blocks 1024..2047:  ligand->ligand aggregate.
// Blocks 2048..2063:  Wc[l] = W[l] @ W_fc[l-block]  (16 = 8 layers x 2 rels)
// Block  2064:        folded bias.
//
// Aggregate algebra: g[f] = sum_s c[s]*x[s,f],
//   c[s] = rsqrt(deg_src[s]) * (1/NL) * sum_{e:src=s} rsqrt(deg_dst[dst_e])
// turning the per-edge gather into a sequential stream of the graph's rows.
__global__ __launch_bounds__(512) void mega_kernel(
    const float* __restrict__ feat_lig, const float* __restrict__ feat_prot,
    const int* __restrict__ src_pl, const int* __restrict__ dst_pl,
    const int* __restrict__ src_ll, const int* __restrict__ dst_ll,
    const float* __restrict__ W_pl, const float* __restrict__ W_ll,
    const float* __restrict__ W_fc,
    const float* __restrict__ b_pl, const float* __restrict__ b_ll,
    const float* __restrict__ b_fc,
    float* __restrict__ g_pl, float* __restrict__ g_ll,
    float* __restrict__ Wc_pl, float* __restrict__ Wc_ll,
    float* __restrict__ bias_out)
{
    __shared__ int    s_cnt_src[NP];
    __shared__ int    s_cnt_dst[NL];
    __shared__ float  s_c[NP];
    __shared__ float4 s_red[16][32];   // also reused as scratch by bias block

    const int bid = blockIdx.x;
    const int tid = threadIdx.x;

    if (bid < 2 * L * B) {
        const int rel = bid >> 10;                 // 0: pl, 1: ll
        const int lb  = bid & 1023;
        const int l = lb >> 7, b = lb & 127;
        const int E  = rel ? ELL_G : EPL_G;
        const int NS = rel ? NL : NP;
        const float* feat = rel ? feat_lig : feat_prot;
        const int* srcA   = rel ? src_ll : src_pl;
        const int* dstA   = rel ? dst_ll : dst_pl;
        float* gout       = rel ? g_ll : g_pl;

        const int* srcp = srcA + (size_t)l * (B * E) + (size_t)b * E;
        const int* dstp = dstA + (size_t)l * (B * E) + (size_t)b * E;

        for (int i = tid; i < NS; i += 512) { s_cnt_src[i] = 0; s_c[i] = 0.f; }
        if (tid < NL) s_cnt_dst[tid] = 0;
        __syncthreads();

        // Edges are block-diagonal per graph: local histogram == global degree.
        int es[2], ed[2];
        int ne = 0;
        for (int e = tid; e < E; e += 512) {
            int s = srcp[e] - b * NS;
            int d = dstp[e] - b * NL;
            es[ne] = s; ed[ne] = d; ne++;
            atomicAdd(&s_cnt_src[s], 1);
            atomicAdd(&s_cnt_dst[d], 1);
        }
        __syncthreads();
        for (int i = 0; i < ne; i++)
            atomicAdd(&s_c[es[i]], rsqrtf((float)s_cnt_dst[ed[i]]));
        __syncthreads();
        for (int i = tid; i < NS; i += 512) {
            int c = s_cnt_src[i];
            s_c[i] = c ? s_c[i] * rsqrtf((float)c) * (1.0f / NL) : 0.f;
        }
        __syncthreads();

        // Streaming weighted sum: wave handles 2 rows/iter (float4/lane,
        // 32 lanes x 16 B = one 512 B row); 8 waves -> 16 rows/iter.
        const int lane = tid & 63;
        const int wave = tid >> 6;
        const int half = lane >> 5;
        const int col  = lane & 31;
        const int slot = wave * 2 + half;          // 0..15
        const float* fb = feat + ((size_t)(l * B + b)) * NS * FIN;

        float4 acc = make_float4(0.f, 0.f, 0.f, 0.f);
#pragma unroll 4
        for (int r0 = 0; r0 < NS; r0 += 16) {
            int r = r0 + slot;
            float w = s_c[r];                      // broadcast, conflict-free
            float4 v = *(const float4*)(fb + (size_t)r * FIN + col * 4);
            acc.x += w * v.x; acc.y += w * v.y;
            acc.z += w * v.z; acc.w += w * v.w;
        }
        s_red[slot][col] = acc;                    // b128, contiguous
        __syncthreads();

        if (tid < FIN) {
            float t = 0.f;
#pragma unroll
            for (int k = 0; k < 16; k++) {
                const float* p = (const float*)&s_red[k][tid >> 2];
                t += p[tid & 3];
            }
            gout[((size_t)(l * B + b)) * FIN + tid] = t;
        }
    } else if (bid < 2 * L * B + 16) {
        // Wc[l,f,o] = sum_h W[l,f,h] * W_fc[l*H+h, o]
        const int q = bid - 2 * L * B;
        const int l = q & 7;
        const float* W = (q >> 3) ? W_ll : W_pl;
        float* outc    = (q >> 3) ? Wc_ll : Wc_pl;
        if (tid < 256) {
            const int f = tid >> 1, o = tid & 1;
            const float* wrow = W + ((size_t)l * FIN + f) * H;
            const float* fc   = W_fc + (size_t)l * H * OUT + o;
            float acc = 0.f;
#pragma unroll 4
            for (int h = 0; h < H; h++)
                acc += wrow[h] * fc[h * OUT];
            outc[((size_t)l * FIN + f) * OUT + o] = acc;
        }
    } else {
        // bias_out[o] = b_fc[o] + sum_{l,h} (b_pl+b_ll)[l,h] * W_fc[l*H+h,o]
        float* r0 = (float*)s_red;                 // 512 floats
        float* r1 = r0 + 512;                      // 512 floats (4 KB < 8 KB)
        float a0 = 0.f, a1 = 0.f;
        for (int i = tid; i < L * H; i += 512) {
            float bs = b_pl[i] + b_ll[i];
            a0 += bs * W_fc[i * OUT];
            a1 += bs * W_fc[i * OUT + 1];
        }
        r0[tid] = a0; r1[tid] = a1;
        __syncthreads();
        for (int s = 256; s > 0; s >>= 1) {
            if (tid < s) { r0[tid] += r0[tid + s]; r1[tid] += r1[tid + s]; }
            __syncthreads();
        }
        if (tid == 0) {
            bias_out[0] = r0[0] + b_fc[0];
            bias_out[1] = r1[0] + b_fc[1];
        }
    }
}

// out[b,o] = sigmoid(bias_out[o] + sum_{l,f} g_pl*Wc_pl + g_ll*Wc_ll)
__global__ __launch_bounds__(256) void final_kernel(
    const float* __restrict__ g_pl, const float* __restrict__ g_ll,
    const float* __restrict__ Wc_pl, const float* __restrict__ Wc_ll,
    const float* __restrict__ bias_out, float* __restrict__ out)
{
    const int b = blockIdx.x;
    const int t = threadIdx.x;
    const int o = t >> 7, f = t & 127;
    float acc = 0.f;
#pragma unroll
    for (int l = 0; l < L; l++) {
        float gp = g_pl[((size_t)(l * B + b)) * FIN + f];
        float gl = g_ll[((size_t)(l * B + b)) * FIN + f];
        acc += gp * Wc_pl[((size_t)l * FIN + f) * OUT + o]
             + gl * Wc_ll[((size_t)l * FIN + f) * OUT + o];
    }
    __shared__ float red[256];
    red[t] = acc;
    __syncthreads();
    for (int s = 64; s > 0; s >>= 1) {
        if (f < s) red[t] += red[t + s];
        __syncthreads();
    }
    if (f == 0) {
        float x = red[o << 7] + bias_out[o];
        out[b * OUT + o] = 1.0f / (1.0f + expf(-x));
    }
}

extern "C" void kernel_launch(void* const* d_in, const int* in_sizes, int n_in,
                              void* d_out, int out_size, void* d_ws, size_t ws_size,
                              hipStream_t stream) {
    const float* feat_lig  = (const float*)d_in[0];
    const float* feat_prot = (const float*)d_in[1];
    const int* src_pl = (const int*)d_in[2];
    const int* dst_pl = (const int*)d_in[3];
    const int* src_ll = (const int*)d_in[4];
    const int* dst_ll = (const int*)d_in[5];
    const float* W_pl = (const float*)d_in[6];
    const float* b_pl = (const float*)d_in[7];
    const float* W_ll = (const float*)d_in[8];
    const float* b_ll = (const float*)d_in[9];
    const float* W_fc = (const float*)d_in[10];
    const float* b_fc = (const float*)d_in[11];
    float* out = (float*)d_out;

    float* ws       = (float*)d_ws;
    float* g_pl     = ws;                            // L*B*FIN = 131072
    float* g_ll     = g_pl + (size_t)L * B * FIN;    // 131072
    float* Wc_pl    = g_ll + (size_t)L * B * FIN;    // L*FIN*OUT = 2048
    float* Wc_ll    = Wc_pl + (size_t)L * FIN * OUT; // 2048
    float* bias_out = Wc_ll + (size_t)L * FIN * OUT; // 2

    mega_kernel<<<dim3(2 * L * B + 17), 512, 0, stream>>>(
        feat_lig, feat_prot, src_pl, dst_pl, src_ll, dst_ll,
        W_pl, W_ll, W_fc, b_pl, b_ll, b_fc,
        g_pl, g_ll, Wc_pl, Wc_ll, bias_out);
    final_kernel<<<dim3(B), 256, 0, stream>>>(g_pl, g_ll, Wc_pl, Wc_ll, bias_out, out);
}

// Round 4
// 227.510 us; speedup vs baseline: 1.2279x; 1.0568x over previous
//
#include <hip/hip_runtime.h>

#define L 8
#define B 128
#define NL 32
#define NP 256
#define EPL_G 1024
#define ELL_G 256
#define FIN 128
#define H 256
#define OUT 2

typedef float f4 __attribute__((ext_vector_type(4)));

__shared__ int s_cnt_src[NP];
__shared__ int s_cnt_dst[NL];
__shared__ float s_c[NP];
__shared__ f4 s_red[16][32];   // reused as scratch by the bias block

// Aggregate algebra: g[f] = sum_s c[s]*x[s,f],
//   c[s] = rsqrt(deg_src[s]) * (1/NL) * sum_{e:src=s} rsqrt(deg_dst[dst_e])
// turning the per-edge gather into a sequential stream of the graph's rows.
template <int REL>
__device__ __forceinline__ void agg_block(
    int l, int b, int tid,
    const float* __restrict__ feat,
    const int* __restrict__ srcA, const int* __restrict__ dstA,
    float* __restrict__ gout)
{
    constexpr int E  = REL ? ELL_G : EPL_G;
    constexpr int NS = REL ? NL : NP;

    const int* srcp = srcA + (size_t)l * (B * E) + (size_t)b * E;
    const int* dstp = dstA + (size_t)l * (B * E) + (size_t)b * E;

    for (int i = tid; i < NS; i += 512) { s_cnt_src[i] = 0; s_c[i] = 0.f; }
    if (tid < NL) s_cnt_dst[tid] = 0;
    __syncthreads();

    // Edges are block-diagonal per graph: local histogram == global degree.
    int es[2], ed[2];
    int ne = 0;
#pragma unroll
    for (int e = tid; e < E; e += 512) {
        int s = srcp[e] - b * NS;
        int d = dstp[e] - b * NL;
        es[ne] = s; ed[ne] = d; ne++;
        atomicAdd(&s_cnt_src[s], 1);
        atomicAdd(&s_cnt_dst[d], 1);
    }
    __syncthreads();
#pragma unroll
    for (int i = 0; i < (E + 511) / 512; i++)
        if (i < ne) atomicAdd(&s_c[es[i]], rsqrtf((float)s_cnt_dst[ed[i]]));
    __syncthreads();
    for (int i = tid; i < NS; i += 512) {
        int c = s_cnt_src[i];
        s_c[i] = c ? s_c[i] * rsqrtf((float)c) * (1.0f / NL) : 0.f;
    }
    __syncthreads();

    // Streaming weighted sum. Each wave covers one 512 B row per half-wave;
    // two rows (r, r+16) per slot per iter -> 2 independent acc chains,
    // 2 outstanding nt-loads per lane per iter. Feature slices are
    // block-exclusive and read once: non-temporal, skip L2 fill.
    const int lane = tid & 63;
    const int wave = tid >> 6;
    const int slot = wave * 2 + (lane >> 5);   // 0..15
    const int col  = lane & 31;
    const float* fb = feat + ((size_t)(l * B + b)) * NS * FIN + col * 4;

    f4 acc0 = 0.f, acc1 = 0.f;
#pragma unroll
    for (int r0 = 0; r0 < NS; r0 += 32) {
        int ra = r0 + slot;
        int rb = ra + 16;
        float wa = s_c[ra];                    // LDS broadcast, conflict-free
        float wb = s_c[rb];
        f4 va = __builtin_nontemporal_load((const f4*)(fb + (size_t)ra * FIN));
        f4 vb = __builtin_nontemporal_load((const f4*)(fb + (size_t)rb * FIN));
        acc0 += wa * va;
        acc1 += wb * vb;
    }
    s_red[slot][col] = acc0 + acc1;            // b128, contiguous
    __syncthreads();

    if (tid < FIN) {
        float t = 0.f;
#pragma unroll
        for (int k = 0; k < 16; k++) {
            const float* p = (const float*)&s_red[k][tid >> 2];
            t += p[tid & 3];
        }
        gout[((size_t)(l * B + b)) * FIN + tid] = t;
    }
}

// Blocks 0..1023: protein->ligand. 1024..2047: ligand->ligand.
// 2048..2063: Wc = W @ W_fc-block. 2064: folded bias.
__global__ __launch_bounds__(512) void mega_kernel(
    const float* __restrict__ feat_lig, const float* __restrict__ feat_prot,
    const int* __restrict__ src_pl, const int* __restrict__ dst_pl,
    const int* __restrict__ src_ll, const int* __restrict__ dst_ll,
    const float* __restrict__ W_pl, const float* __restrict__ W_ll,
    const float* __restrict__ W_fc,
    const float* __restrict__ b_pl, const float* __restrict__ b_ll,
    const float* __restrict__ b_fc,
    float* __restrict__ g_pl, float* __restrict__ g_ll,
    float* __restrict__ Wc_pl, float* __restrict__ Wc_ll,
    float* __restrict__ bias_out)
{
    const int bid = blockIdx.x;
    const int tid = threadIdx.x;

    if (bid < L * B) {
        agg_block<0>(bid >> 7, bid & 127, tid, feat_prot, src_pl, dst_pl, g_pl);
    } else if (bid < 2 * L * B) {
        const int lb = bid - L * B;
        agg_block<1>(lb >> 7, lb & 127, tid, feat_lig, src_ll, dst_ll, g_ll);
    } else if (bid < 2 * L * B + 16) {
        // Wc[l,f,o] = sum_h W[l,f,h] * W_fc[l*H+h, o]   (graph-mean commutes
        // with the linear map, so the conv weight folds into the FC)
        const int q = bid - 2 * L * B;
        const int l = q & 7;
        const float* W = (q >> 3) ? W_ll : W_pl;
        float* outc    = (q >> 3) ? Wc_ll : Wc_pl;
        if (tid < 256) {
            const int f = tid >> 1, o = tid & 1;
            const float* wrow = W + ((size_t)l * FIN + f) * H;
            const float* fc   = W_fc + (size_t)l * H * OUT + o;
            float acc = 0.f;
#pragma unroll 4
            for (int h = 0; h < H; h++)
                acc += wrow[h] * fc[h * OUT];
            outc[((size_t)l * FIN + f) * OUT + o] = acc;
        }
    } else {
        // bias_out[o] = b_fc[o] + sum_{l,h} (b_pl+b_ll)[l,h] * W_fc[l*H+h,o]
        float* r0 = (float*)s_red;                 // 512 floats
        float* r1 = r0 + 512;                      // 512 floats (4 KB < 8 KB)
        float a0 = 0.f, a1 = 0.f;
        for (int i = tid; i < L * H; i += 512) {
            float bs = b_pl[i] + b_ll[i];
            a0 += bs * W_fc[i * OUT];
            a1 += bs * W_fc[i * OUT + 1];
        }
        r0[tid] = a0; r1[tid] = a1;
        __syncthreads();
        for (int s = 256; s > 0; s >>= 1) {
            if (tid < s) { r0[tid] += r0[tid + s]; r1[tid] += r1[tid + s]; }
            __syncthreads();
        }
        if (tid == 0) {
            bias_out[0] = r0[0] + b_fc[0];
            bias_out[1] = r1[0] + b_fc[1];
        }
    }
}

// out[b,o] = sigmoid(bias_out[o] + sum_{l,f} g_pl*Wc_pl + g_ll*Wc_ll)
__global__ __launch_bounds__(256) void final_kernel(
    const float* __restrict__ g_pl, const float* __restrict__ g_ll,
    const float* __restrict__ Wc_pl, const float* __restrict__ Wc_ll,
    const float* __restrict__ bias_out, float* __restrict__ out)
{
    const int b = blockIdx.x;
    const int t = threadIdx.x;
    const int o = t >> 7, f = t & 127;
    float acc = 0.f;
#pragma unroll
    for (int l = 0; l < L; l++) {
        float gp = g_pl[((size_t)(l * B + b)) * FIN + f];
        float gl = g_ll[((size_t)(l * B + b)) * FIN + f];
        acc += gp * Wc_pl[((size_t)l * FIN + f) * OUT + o]
             + gl * Wc_ll[((size_t)l * FIN + f) * OUT + o];
    }
    __shared__ float red[256];
    red[t] = acc;
    __syncthreads();
    for (int s = 64; s > 0; s >>= 1) {
        if (f < s) red[t] += red[t + s];
        __syncthreads();
    }
    if (f == 0) {
        float x = red[o << 7] + bias_out[o];
        out[b * OUT + o] = 1.0f / (1.0f + expf(-x));
    }
}

extern "C" void kernel_launch(void* const* d_in, const int* in_sizes, int n_in,
                              void* d_out, int out_size, void* d_ws, size_t ws_size,
                              hipStream_t stream) {
    const float* feat_lig  = (const float*)d_in[0];
    const float* feat_prot = (const float*)d_in[1];
    const int* src_pl = (const int*)d_in[2];
    const int* dst_pl = (const int*)d_in[3];
    const int* src_ll = (const int*)d_in[4];
    const int* dst_ll = (const int*)d_in[5];
    const float* W_pl = (const float*)d_in[6];
    const float* b_pl = (const float*)d_in[7];
    const float* W_ll = (const float*)d_in[8];
    const float* b_ll = (const float*)d_in[9];
    const float* W_fc = (const float*)d_in[10];
    const float* b_fc = (const float*)d_in[11];
    float* out = (float*)d_out;

    float* ws       = (float*)d_ws;
    float* g_pl     = ws;                            // L*B*FIN = 131072
    float* g_ll     = g_pl + (size_t)L * B * FIN;    // 131072
    float* Wc_pl    = g_ll + (size_t)L * B * FIN;    // L*FIN*OUT = 2048
    float* Wc_ll    = Wc_pl + (size_t)L * FIN * OUT; // 2048
    float* bias_out = Wc_ll + (size_t)L * FIN * OUT; // 2

    mega_kernel<<<dim3(2 * L * B + 17), 512, 0, stream>>>(
        feat_lig, feat_prot, src_pl, dst_pl, src_ll, dst_ll,
        W_pl, W_ll, W_fc, b_pl, b_ll, b_fc,
        g_pl, g_ll, Wc_pl, Wc_ll, bias_out);
    final_kernel<<<dim3(B), 256, 0, stream>>>(g_pl, g_ll, Wc_pl, Wc_ll, bias_out, out);
}